// Round 4
// baseline (1503.690 us; speedup 1.0000x reference)
//
#include <hip/hip_runtime.h>

#define NROWS 2048
#define DR2   512
#define TSTEPS 64
#define NK    ((size_t)NROWS * DR2)

typedef _Float16 half8 __attribute__((ext_vector_type(8)));
typedef float floatx4 __attribute__((ext_vector_type(4)));

// s_waitcnt: vmcnt=N, lgkm/exp unconstrained (gfx9 encoding).
#define WAITVM(N) __builtin_amdgcn_s_waitcnt(((N)&15) | (((N)>>4)<<14) | (7<<4) | (15<<8))

// Async global->LDS, 16 B/lane. LDS base wave-uniform; HW scatters lane i at
// base + 16*i.
static __device__ __forceinline__ void gload_lds16(const _Float16* g, _Float16* l) {
    __builtin_amdgcn_global_load_lds(
        (const __attribute__((address_space(1))) unsigned int*)g,
        (__attribute__((address_space(3))) unsigned int*)l,
        16, 0, 0);
}

// Builds:
//  Wq  [4 J][16 c][8 tile][64 lane][8 e] f16 : W_top permuted to exact MFMA
//      b-frag order, so evolve's staging is lane-linear and frag reads are
//      stride-1. element = w1[k][j], j=J*128+tile*16+(lane&15), k=c*32+(lane>>4)*8+e
//  Wbot[j][kk] f16 row-major B^T of bottom half: w1[512+kk][j]  (for precompute)
__global__ void prep_w(const float* __restrict__ w1, _Float16* __restrict__ Wq,
                       _Float16* __restrict__ Wbot) {
    int idx = blockIdx.x * 256 + threadIdx.x;           // 0 .. 524287
    if (idx < 262144) {
        int e   = idx & 7;
        int ln  = (idx >> 3) & 63;
        int tl  = (idx >> 9) & 7;
        int c   = (idx >> 12) & 15;
        int J   = (idx >> 16) & 3;
        int j   = J * 128 + tl * 16 + (ln & 15);
        int k   = c * 32 + (ln >> 4) * 8 + e;
        Wq[idx] = (_Float16)w1[k * DR2 + j];
    } else {
        int i  = idx - 262144;
        int kk = i & 511;
        int j  = i >> 9;
        Wbot[i] = (_Float16)w1[(512 + kk) * DR2 + j];
    }
}

// h16 = (f16)h0 ; out0[0] = h0 (reference stores h0, NOT states[0])
__global__ void prep_h0(const float* __restrict__ h0, _Float16* __restrict__ h16,
                        float* __restrict__ out0) {
    int idx = blockIdx.x * 256 + threadIdx.x;   // per float4
    float4 v = ((const float4*)h0)[idx];
    ((float4*)out0)[idx] = v;
    union { uint2 u; _Float16 h[4]; } p;
    p.h[0] = (_Float16)v.x; p.h[1] = (_Float16)v.y;
    p.h[2] = (_Float16)v.z; p.h[3] = (_Float16)v.w;
    ((uint2*)h16)[idx] = p.u;
}

// S[t] = static_t @ w1_bot, all t: [131072,512] @ [512,512]. 128x128 tiles.
// S[0] -> S0 (out0 slice-1 overlay); S[t>=1] -> Srest[t-1] (out2 overlay).
#define KPP 128
__global__ __launch_bounds__(256) void precompute_S(
    const float* __restrict__ sta, const _Float16* __restrict__ Wbot,
    float* S0, float* Srest)
{
    __shared__ _Float16 Ash[128 * KPP];   // 32 KB
    __shared__ _Float16 Bsh[128 * KPP];   // 32 KB
    const int tid = threadIdx.x, lane = tid & 63, wv = tid >> 6;
    const int waveM = wv & 1, waveJ = wv >> 1;
    const int lm = lane & 15, quad = lane >> 4;
    const int j0  = blockIdx.x * 128;
    const int mr0 = blockIdx.y * 128;           // global row = t*2048 + n
    const int t  = mr0 >> 11;
    const int n0 = mr0 & 2047;

    floatx4 acc[4][4] = {};

    for (int ph = 0; ph < 4; ++ph) {
        __syncthreads();
        #pragma unroll
        for (int i = 0; i < 8; ++i) {
            int rp = wv * 32 + i * 4;
            int r  = rp + (lane >> 4);
            int k8 = (lane & 15) ^ (r & 7);
            gload_lds16(Wbot + (size_t)(j0 + r) * 512 + ph * KPP + k8 * 8,
                        Bsh + rp * KPP);
        }
        #pragma unroll
        for (int p = 0; p < 8; ++p) {
            int c = p * 256 + tid;
            int r = c >> 4, c8p = c & 15;
            int k8 = c8p ^ (r & 7);
            size_t g = ((size_t)(mr0 + r)) * DR2 + ph * KPP + k8 * 8;
            float4 lo = *(const float4*)(sta + g);
            float4 hi = *(const float4*)(sta + g + 4);
            union { half8 v; _Float16 h[8]; } u;
            u.h[0]=(_Float16)lo.x; u.h[1]=(_Float16)lo.y;
            u.h[2]=(_Float16)lo.z; u.h[3]=(_Float16)lo.w;
            u.h[4]=(_Float16)hi.x; u.h[5]=(_Float16)hi.y;
            u.h[6]=(_Float16)hi.z; u.h[7]=(_Float16)hi.w;
            *(half8*)(Ash + r * KPP + (c8p << 3)) = u.v;
        }
        __syncthreads();

        #pragma unroll
        for (int ks = 0; ks < 4; ++ks) {
            int c8 = ks * 4 + quad;
            half8 a[4], b[4];
            #pragma unroll
            for (int tm = 0; tm < 4; ++tm) {
                int ra = waveM * 64 + tm * 16 + lm;
                a[tm] = *(const half8*)(Ash + ra * KPP + (((c8 ^ (ra & 7))) << 3));
            }
            #pragma unroll
            for (int tj = 0; tj < 4; ++tj) {
                int rb = waveJ * 64 + tj * 16 + lm;
                b[tj] = *(const half8*)(Bsh + rb * KPP + (((c8 ^ (rb & 7))) << 3));
            }
            #pragma unroll
            for (int tm = 0; tm < 4; ++tm)
                #pragma unroll
                for (int tj = 0; tj < 4; ++tj)
                    acc[tm][tj] = __builtin_amdgcn_mfma_f32_16x16x32_f16(
                        a[tm], b[tj], acc[tm][tj], 0, 0, 0);
        }
    }

    float* dst = (t == 0) ? S0 : (Srest + (size_t)(t - 1) * NK);
    #pragma unroll
    for (int tm = 0; tm < 4; ++tm)
        #pragma unroll
        for (int r = 0; r < 4; ++r) {
            int n = n0 + waveM * 64 + tm * 16 + quad * 4 + r;
            #pragma unroll
            for (int tj = 0; tj < 4; ++tj) {
                int j = j0 + waveJ * 64 + tj * 16 + lm;
                dst[(size_t)n * DR2 + j] = acc[tm][tj][r];
            }
        }
}

// ---- The whole 64-step recurrence in ONE kernel. ----
// Row-chains are independent: WG b owns rows nb0=b*16..+16, loops t=0..63.
// h lives in LDS (ping-pong, swizzled 16B chunks); each wave owns j-slice
// J=wv (128 cols) and streams its frag-ordered B slice (128 KB/step) from L2.
// A-frags for all K=512 are held in 64 VGPRs per lane, reloaded once per step.
__global__ __launch_bounds__(256, 1) void evolve(
    const float* __restrict__ thr,      // [T,N]
    const _Float16* __restrict__ Wq,    // frag-ordered W_top
    const _Float16* __restrict__ h16,   // [N,512] f16 initial h0
    const float* S0,                    // S[0] (= out0 slice 1 overlay)
    float* out0, float* out1, float* out2)   // no __restrict__: S overlays
{
    __shared__ _Float16 hA[2][16 * 512];   // 2 x 16 KB
    __shared__ _Float16 Bst[4][4096];      // 8 KB per wave (one 32-k chunk)

    const int tid  = threadIdx.x;
    const int lane = tid & 63;
    const int wv   = tid >> 6;             // wave = j-slice J
    const int lm   = lane & 15;
    const int quad = lane >> 4;
    const int nb0  = blockIdx.x * 16;

    // ---- init hA[0] <- h16 rows nb0..nb0+15, swizzled ----
    #pragma unroll
    for (int i = 0; i < 4; ++i) {
        int pos = tid + i * 256;           // 0..1023 = 16 rows x 64 chunks
        int r = pos >> 6, k8 = pos & 63;
        uint4 v = *(const uint4*)(h16 + (size_t)(nb0 + r) * DR2 + k8 * 8);
        *(uint4*)(&hA[0][r * 512 + ((k8 ^ (r & 7)) << 3)]) = v;
    }
    __syncthreads();

    const _Float16* wq = Wq + (size_t)wv * 65536;   // this wave's J slice
    const float DECAY = 0.60653065971263342f;
    int p = 0;

    for (int t = 0; t < TSTEPS; ++t) {
        const float* S_t = (t == 0) ? S0 : (out2 + (size_t)(t - 1) * NK);

        // ---- A-frags for the whole step (64 VGPRs) ----
        half8 af[16];
        #pragma unroll
        for (int c = 0; c < 16; ++c)
            af[c] = *(const half8*)(&hA[p][lm * 512 + (((c * 4 + quad) ^ (lm & 7)) << 3)]);

        // ---- epilogue operands (compiler schedules; reg-dep waits are exact) ----
        float thr_v = thr[t * NROWS + nb0 + lm];
        float sv[8][4];
        #pragma unroll
        for (int tl = 0; tl < 8; ++tl)
            #pragma unroll
            for (int r = 0; r < 4; ++r)
                sv[tl][r] = S_t[(size_t)(nb0 + quad * 4 + r) * DR2
                                + wv * 128 + tl * 16 + lm];

        // ---- K-loop: 16 chunks of 32k, wave-private staging, no barriers ----
        floatx4 acc[8] = {};
        for (int c = 0; c < 16; ++c) {
            #pragma unroll
            for (int g = 0; g < 8; ++g)
                gload_lds16(wq + c * 4096 + g * 512 + lane * 8, Bst[wv] + g * 512);
            WAITVM(0);                      // chunk resident (conservative-safe)
            #pragma unroll
            for (int tl = 0; tl < 8; ++tl) {
                half8 b = *(const half8*)(&Bst[wv][tl * 512 + lane * 8]);
                acc[tl] = __builtin_amdgcn_mfma_f32_16x16x32_f16(af[c], b, acc[tl], 0, 0, 0);
            }
        }

        // ---- epilogue: gate, h update (LDS), outputs ----
        #pragma unroll
        for (int r = 0; r < 4; ++r) {
            int m = quad * 4 + r;
            int n = nb0 + m;
            float thv = __shfl(thr_v, m);
            float om  = 1.0f - thv;
            #pragma unroll
            for (int tl = 0; tl < 8; ++tl) {
                int jj = wv * 128 + tl * 16 + lm;
                int sw = m * 512 + ((((jj >> 3) ^ (m & 7))) << 3) + (jj & 7);
                float hp = (float)hA[p][sw];
                float z  = (acc[tl][r] + sv[tl][r]) * thv + hp * om;
                float hn = DECAY / (1.0f + __expf(-z));
                hA[p ^ 1][sw] = (_Float16)hn;
                if (t >= 1) {
                    size_t o = ((size_t)t * NROWS + n) * DR2 + jj;
                    out0[o] = hn;
                    out2[o - NK] = hn - hp;        // slice t-1 (overwrites S[t])
                }
                if (t == 63) out1[(size_t)n * DR2 + jj] = hn;
            }
        }
        __syncthreads();                    // h[p^1] complete; drains stores
        p ^= 1;
    }
}

extern "C" void kernel_launch(void* const* d_in, const int* in_sizes, int n_in,
                              void* d_out, int out_size, void* d_ws, size_t ws_size,
                              hipStream_t stream) {
    const float* d_static = (const float*)d_in[0];
    const float* d_thr    = (const float*)d_in[1];
    const float* d_h0     = (const float*)d_in[2];
    const float* d_w1     = (const float*)d_in[3];

    float* out0 = (float*)d_out;                       // [64,2048,512]
    float* out1 = out0 + (size_t)TSTEPS * NK;          // [2048,512]
    float* out2 = out1 + NK;                           // [63,2048,512]

    _Float16* Wq   = (_Float16*)d_ws;                  // 512 KB
    _Float16* Wbot = Wq + 262144;                      // 512 KB
    _Float16* h16  = Wbot + 262144;                    // 2 MB

    float* S0 = out0 + NK;   // S[0] overlay (read at t=0, rewritten at t=1)

    prep_w<<<2048, 256, 0, stream>>>(d_w1, Wq, Wbot);
    prep_h0<<<1024, 256, 0, stream>>>(d_h0, h16, out0);
    precompute_S<<<dim3(4, 1024), 256, 0, stream>>>(d_static, Wbot, S0, out2);
    evolve<<<128, 256, 0, stream>>>(d_thr, Wq, h16, S0, out0, out1, out2);
}